// Round 6
// baseline (236.850 us; speedup 1.0000x reference)
//
#include <hip/hip_runtime.h>

// LengthRegulator: B=32, T=512, D=512, max_len=2048 (fixed by the problem).
// out[b, t, :] = x[b, searchsorted_right(cumsum(duration[b]), t), :] for
// t < sum(duration[b]), else zeros. mel_lengths[b] = max(sum, 1), stored as
// float at the tail of d_out (harness reads whole buffer as float32).
//
// *** INSTRUMENTATION ROUND ***
// Rounds 0-5: five structurally different copies all ran at the same
// effective ~2 TB/s; the harness poison fill reports 6.6 TB/s BUT its
// WRITE_SIZE is EXACTLY 4x the output-buffer size (524288.5 KB vs
// 131072.125 KB incl. the 128 B mel tail) -- so either the harness truly
// writes 512 MiB (machine fast, our copy stalled) or TCC counters are
// 4x-inflated here (machine really ~1.65 TB/s, we are already at its
// roofline). To distinguish: this round keeps the R5 kernels EXACTLY and
// adds a ~50 us dependent-FMA spin tail (asm-sunk, not DCE-able) to
// lr_copy_kernel so it crosses the rocprof top-5 duration cutoff and
// reveals its own WRITE_SIZE / FETCH_SIZE / dur.
//   WRITE_SIZE ~= 131072 KB -> counters truthful -> real stall, keep digging.
//   WRITE_SIZE ~= 524288 KB -> 4x inflation -> fill==ours==~1.6-2 TB/s
//                              -> controllable part already at roofline.

#define BB      32
#define TT      512
#define DD      512
#define MAXLEN  2048
#define RPF     (DD / 4)               // 128 f4 per frame row
#define NF4     (BB * MAXLEN * RPF)    // 2^23 flat f4 elements
#define CBLK    512
#define CTH     (CBLK * 256)           // 131072 copy threads
#define STEPS   (NF4 / CTH)            // 64 grid-stride steps
#define SPIN    32000                  // dependent FMAs (~50 us at 4 cyc/FMA)

typedef float f4 __attribute__((ext_vector_type(4)));

__global__ __launch_bounds__(512) void lr_scan_kernel(
    const int* __restrict__ dur, int* __restrict__ idxt,
    float* __restrict__ mel_out) {
  __shared__ int wsum[8];
  const int b    = blockIdx.x;
  const int tid  = threadIdx.x;
  const int lane = tid & 63;
  const int wid  = tid >> 6;

  const int d = dur[b * TT + tid];
  int v = d;
  // Inclusive scan within the 64-lane wave (6 shfl steps, no barriers).
#pragma unroll
  for (int off = 1; off < 64; off <<= 1) {
    int n = __shfl_up(v, off, 64);
    if (lane >= off) v += n;
  }
  if (lane == 63) wsum[wid] = v;
  __syncthreads();

  int woff = 0, dsum = 0;
#pragma unroll
  for (int i = 0; i < 8; ++i) {
    int w = wsum[i];
    dsum += w;
    if (i < wid) woff += w;
  }
  v += woff;  // inclusive cumsum at phoneme tid

  if (tid == 0) mel_out[b] = (float)(dsum > 1 ? dsum : 1);

  // Scatter: phoneme tid owns output frames [v - d, v), truncated at MAXLEN.
  int start = v - d;
  int end   = v;
  if (start > MAXLEN) start = MAXLEN;
  if (end   > MAXLEN) end   = MAXLEN;
  int* row = idxt + b * MAXLEN;
  for (int t = start; t < end; ++t) row[t] = tid;
  // Padding tail [dsum, MAXLEN): coalesced -1 fill.
  for (int t = dsum + tid; t < MAXLEN; t += TT) row[t] = -1;
}

__global__ __launch_bounds__(256) void lr_copy_kernel(
    const int* __restrict__ idxt, const f4* __restrict__ x,
    f4* __restrict__ out) {
  const int g = blockIdx.x * 256 + threadIdx.x;
  const f4 zero = {0.f, 0.f, 0.f, 0.f};
  float spin_seed = 0.f;

  for (int s = 0; s < STEPS; s += 8) {
    // Phase 1: 8 independent frame-index loads (wave-uniform, L2-hot).
    int idx[8];
#pragma unroll
    for (int u = 0; u < 8; ++u) {
      const size_t e = (size_t)g + (size_t)(s + u) * CTH;
      idx[u] = idxt[e >> 7];
    }
    // Phase 2: 8 independent gathers from x (1 KiB contiguous per wave).
    f4 v[8];
#pragma unroll
    for (int u = 0; u < 8; ++u) {
      const size_t e = (size_t)g + (size_t)(s + u) * CTH;
      v[u] = zero;
      if (idx[u] >= 0) {
        const size_t b = e >> 18;
        v[u] = x[(b * TT + (size_t)idx[u]) * RPF + (e & (RPF - 1))];
      }
    }
    // Phase 3: 8 plain streaming stores (fill mode).
#pragma unroll
    for (int u = 0; u < 8; ++u) {
      const size_t e = (size_t)g + (size_t)(s + u) * CTH;
      out[e] = v[u];
      spin_seed += v[u][0];
    }
  }

  // --- instrumentation spin: dependent FMA chain, asm-sunk (no DCE). ---
  // Purpose: push this dispatch above the rocprof top-5 duration cutoff so
  // its true WRITE_SIZE/FETCH_SIZE/dur become visible. Remove next round.
  float acc = spin_seed;
  for (int i = 0; i < SPIN; ++i) {
    acc = __builtin_fmaf(acc, 1.0000001f, 1e-7f);
  }
  asm volatile("" :: "v"(acc));
}

extern "C" void kernel_launch(void* const* d_in, const int* in_sizes, int n_in,
                              void* d_out, int out_size, void* d_ws, size_t ws_size,
                              hipStream_t stream) {
  const float* x   = (const float*)d_in[0];
  const int*   dur = (const int*)d_in[1];
  // d_in[2] is max_len (=2048), static; hard-coded.
  float* out = (float*)d_out;
  float* mel_out = out + (size_t)BB * MAXLEN * DD;  // tail: 32 floats
  int* idxt = (int*)d_ws;                           // 32*2048*4 = 256 KiB

  lr_scan_kernel<<<BB, 512, 0, stream>>>(dur, idxt, mel_out);
  lr_copy_kernel<<<CBLK, 256, 0, stream>>>(idxt, (const f4*)x, (f4*)out);
}

// Round 7
// 168.361 us; speedup vs baseline: 1.4068x; 1.4068x over previous
//
#include <hip/hip_runtime.h>

// LengthRegulator: B=32, T=512, D=512, max_len=2048 (fixed by the problem).
// out[b, t, :] = x[b, searchsorted_right(cumsum(duration[b]), t), :] for
// t < sum(duration[b]), else zeros. mel_lengths[b] = max(sum, 1), stored as
// float at the tail of d_out (harness reads whole buffer as float32).
//
// R6 ground truth: counters truthful. Copy traffic ideal (FETCH 37 MB,
// WRITE 131072 KB exactly); copy-proper ~55 us = 3.1 TB/s vs fill's proven
// 6.6 TB/s. The 512 MiB fill is the d_ws poison; it evicts x from L3 every
// iteration, so the copy's reads are HBM-cold and interleave with its write
// stream (DRAM turnaround + in-order wave stalls on vmcnt).
//
// THIS ROUND'S SINGLE VARIABLE: warm x into L2/L3 before the copy.
//   A) lr_scan_prefetch_kernel (160 blocks x 512):
//        blocks 0-31:  R5's proven wave-shfl scan -> idxt table + mel tail.
//        blocks 32-159: stream all 32 MiB of x (asm-sunk, 8-deep unroll,
//        exact coverage: 128 blk x 512 thr x 32 iters x 16 B = 32 MiB).
//      ~6 us, overlaps the scan's own 3 us.
//   B) lr_copy_kernel: BYTE-IDENTICAL to R5. Its reads now hit L3 -> DRAM
//      sees a near-pure write stream during the copy.
// If copy drops 55 -> ~32 us, mixing/latency theory confirmed. If null,
// every structural axis is falsified and the controllable part is at its
// harness ceiling.

#define BB      32
#define TT      512
#define DD      512
#define MAXLEN  2048
#define RPF     (DD / 4)               // 128 f4 per frame row
#define NF4     (BB * MAXLEN * RPF)    // 2^23 flat f4 elements
#define CBLK    512
#define CTH     (CBLK * 256)           // 131072 copy threads
#define STEPS   (NF4 / CTH)            // 64 grid-stride steps
#define SBLK    32                     // scan blocks
#define PBLK    128                    // prefetch blocks
#define XF4     (BB * TT * RPF)        // 2^21 f4 elements of x

typedef float f4 __attribute__((ext_vector_type(4)));

__global__ __launch_bounds__(512) void lr_scan_prefetch_kernel(
    const int* __restrict__ dur, const f4* __restrict__ x,
    int* __restrict__ idxt, float* __restrict__ mel_out) {
  const int tid = threadIdx.x;

  if (blockIdx.x >= SBLK) {
    // ---- prefetch role: stream x into L2/L3, exact coverage, no DCE ----
    const int ptid = (blockIdx.x - SBLK) * 512 + tid;   // 0..65535
    float acc = 0.f;
#pragma unroll
    for (int ph = 0; ph < 4; ++ph) {
      f4 a[8];
#pragma unroll
      for (int u = 0; u < 8; ++u) {
        a[u] = x[(size_t)(ph * 8 + u) * (PBLK * 512) + ptid];
      }
#pragma unroll
      for (int u = 0; u < 8; ++u) acc += a[u][0];
    }
    asm volatile("" :: "v"(acc));   // keep loads live (rule: no DCE ablation)
    return;
  }

  // ---- scan role: identical to R5's proven scan ----
  __shared__ int wsum[8];
  const int b    = blockIdx.x;
  const int lane = tid & 63;
  const int wid  = tid >> 6;

  const int d = dur[b * TT + tid];
  int v = d;
#pragma unroll
  for (int off = 1; off < 64; off <<= 1) {
    int n = __shfl_up(v, off, 64);
    if (lane >= off) v += n;
  }
  if (lane == 63) wsum[wid] = v;
  __syncthreads();

  int woff = 0, dsum = 0;
#pragma unroll
  for (int i = 0; i < 8; ++i) {
    int w = wsum[i];
    dsum += w;
    if (i < wid) woff += w;
  }
  v += woff;  // inclusive cumsum at phoneme tid

  if (tid == 0) mel_out[b] = (float)(dsum > 1 ? dsum : 1);

  // Scatter: phoneme tid owns output frames [v - d, v), truncated at MAXLEN.
  int start = v - d;
  int end   = v;
  if (start > MAXLEN) start = MAXLEN;
  if (end   > MAXLEN) end   = MAXLEN;
  int* row = idxt + b * MAXLEN;
  for (int t = start; t < end; ++t) row[t] = tid;
  // Padding tail [dsum, MAXLEN): coalesced -1 fill.
  for (int t = dsum + tid; t < MAXLEN; t += TT) row[t] = -1;
}

__global__ __launch_bounds__(256) void lr_copy_kernel(
    const int* __restrict__ idxt, const f4* __restrict__ x,
    f4* __restrict__ out) {
  const int g = blockIdx.x * 256 + threadIdx.x;
  const f4 zero = {0.f, 0.f, 0.f, 0.f};

  for (int s = 0; s < STEPS; s += 8) {
    // Phase 1: 8 independent frame-index loads (wave-uniform, L2-hot).
    int idx[8];
#pragma unroll
    for (int u = 0; u < 8; ++u) {
      const size_t e = (size_t)g + (size_t)(s + u) * CTH;
      idx[u] = idxt[e >> 7];
    }
    // Phase 2: 8 independent gathers from x (now L2/L3-hot after prefetch).
    f4 v[8];
#pragma unroll
    for (int u = 0; u < 8; ++u) {
      const size_t e = (size_t)g + (size_t)(s + u) * CTH;
      v[u] = zero;
      if (idx[u] >= 0) {
        const size_t b = e >> 18;
        v[u] = x[(b * TT + (size_t)idx[u]) * RPF + (e & (RPF - 1))];
      }
    }
    // Phase 3: 8 plain streaming stores (fill mode).
#pragma unroll
    for (int u = 0; u < 8; ++u) {
      const size_t e = (size_t)g + (size_t)(s + u) * CTH;
      out[e] = v[u];
    }
  }
}

extern "C" void kernel_launch(void* const* d_in, const int* in_sizes, int n_in,
                              void* d_out, int out_size, void* d_ws, size_t ws_size,
                              hipStream_t stream) {
  const float* x   = (const float*)d_in[0];
  const int*   dur = (const int*)d_in[1];
  // d_in[2] is max_len (=2048), static; hard-coded.
  float* out = (float*)d_out;
  float* mel_out = out + (size_t)BB * MAXLEN * DD;  // tail: 32 floats
  int* idxt = (int*)d_ws;                           // 32*2048*4 = 256 KiB

  lr_scan_prefetch_kernel<<<SBLK + PBLK, 512, 0, stream>>>(
      dur, (const f4*)x, idxt, mel_out);
  lr_copy_kernel<<<CBLK, 256, 0, stream>>>(idxt, (const f4*)x, (f4*)out);
}